// Round 2
// baseline (266.880 us; speedup 1.0000x reference)
//
#include <hip/hip_runtime.h>
#include <math.h>

#define B_   32
#define C_   64
#define H_   224
#define W_   224
#define HW_  (H_*W_)          // 50176
#define HW4_ (HW_/4)          // 12544
#define G_   36
#define CHUNKS_ 28
#define F4_PER_CHUNK_ (HW4_/CHUNKS_)   // 448 = 256 + 192

typedef float f4v __attribute__((ext_vector_type(4)));

// ---------------- kernel 1: channel mean (plain cached loads) ----------------
__global__ __launch_bounds__(256) void k_mean(const float* __restrict__ x,
                                              float* __restrict__ a) {
    int b = blockIdx.x / 49;                      // 49 blocks per image (49*256 = 12544 float4)
    int i = (blockIdx.x % 49) * 256 + threadIdx.x;
    const f4v* x4 = reinterpret_cast<const f4v*>(x) + (size_t)b * C_ * HW4_ + i;
    f4v s = {0.f, 0.f, 0.f, 0.f};
    #pragma unroll 8
    for (int c = 0; c < C_; ++c) {
        s += x4[(size_t)c * HW4_];
    }
    s *= (1.0f / 64.0f);
    reinterpret_cast<f4v*>(a)[(size_t)b * HW4_ + i] = s;
}

#define PAIR_LISTS \
    const int P0[G_] = {0,0,0,0,0,0,0,0, 1,1,1,1,1,1,1, 2,2,2,2,2,2, 3,3,3,3,3, 4,4,4,4, 5,5,5, 6,6, 7}; \
    const int P1[G_] = {1,2,3,4,5,6,7,8, 2,3,4,5,6,7,8, 3,4,5,6,7,8, 4,5,6,7,8, 5,6,7,8, 6,7,8, 7,8, 8};

// Load the 3x6 neighborhood (rows up/center/down, cols w0-1 .. w0+4, clamped)
// for the float4 of pixels starting at (h, w0=4*c4).
__device__ __forceinline__ void load_rows(const float* __restrict__ ab, int j,
                                          float* RU, float* RC, float* RD) {
    int h  = j / 56;
    int c4 = j - h * 56;
    int w0 = c4 * 4;
    const float* rowC = ab + h * W_;
    const float* rowU = ab + (h > 0      ? h - 1 : 0     ) * W_;
    const float* rowD = ab + (h < H_ - 1 ? h + 1 : H_ - 1) * W_;
    int wl = w0 > 0        ? w0 - 1 : 0;
    int wr = w0 + 4 < W_   ? w0 + 4 : W_ - 1;
    f4v cC = *reinterpret_cast<const f4v*>(rowC + w0);
    f4v cU = *reinterpret_cast<const f4v*>(rowU + w0);
    f4v cD = *reinterpret_cast<const f4v*>(rowD + w0);
    RC[0] = rowC[wl]; RC[1] = cC.x; RC[2] = cC.y; RC[3] = cC.z; RC[4] = cC.w; RC[5] = rowC[wr];
    RU[0] = rowU[wl]; RU[1] = cU.x; RU[2] = cU.y; RU[3] = cU.z; RU[4] = cU.w; RU[5] = rowU[wr];
    RD[0] = rowD[wl]; RD[1] = cD.x; RD[2] = cD.y; RD[3] = cD.z; RD[4] = cD.w; RD[5] = rowD[wr];
}

// GLCM channel value for pixel jj (0..3) within the float4, channel idx 0..8:
// nn0=C[j+1] nn1=C[j+2] nn2=D[j+1] nn3=D[j+2] nn4=C[j] nn5=U[j+1] nn6=D[j+2] nn7=U[j+2] nn8=U[j]
__device__ __forceinline__ float glcm_val(const float* RU, const float* RC,
                                          const float* RD, int jj, int ch) {
    switch (ch) {
        case 0: return RC[jj+1];
        case 1: return RC[jj+2];
        case 2: return RD[jj+1];
        case 3: return RD[jj+2];
        case 4: return RC[jj];
        case 5: return RU[jj+1];
        case 6: return RD[jj+2];
        case 7: return RU[jj+2];
        default: return RU[jj];
    }
}

// ---------------- kernel 2: per-(b,chunk) partial sums of relu(bn(grouped conv)) ----------------
__global__ __launch_bounds__(256) void k_sums(const float* __restrict__ a,
                                              const float* __restrict__ gw,
                                              const float* __restrict__ bng_g, const float* __restrict__ bng_b,
                                              const float* __restrict__ bng_m, const float* __restrict__ bng_v,
                                              float* __restrict__ partial) {
    PAIR_LISTS
    int b = blockIdx.x / CHUNKS_;
    int chunk = blockIdx.x % CHUNKS_;
    int t = threadIdx.x;
    __shared__ float sA0[G_], sA1[G_], sB[G_];
    __shared__ float red[4 * G_];
    if (t < G_) {
        float sg = bng_g[t] / sqrtf(bng_v[t] + 1e-5f);
        sA0[t] = gw[2*t+0] * sg;
        sA1[t] = gw[2*t+1] * sg;
        sB[t]  = bng_b[t] - bng_m[t] * sg;
    }
    __syncthreads();
    const float* ab = a + (size_t)b * HW_;
    float acc[G_];
    #pragma unroll
    for (int g = 0; g < G_; ++g) acc[g] = 0.f;

    #pragma unroll 1
    for (int k = 0; k < 2; ++k) {
        int idx = k * 256 + t;
        if (idx < F4_PER_CHUNK_) {          // k==1: only t<192
            int j = chunk * F4_PER_CHUNK_ + idx;
            float RU[6], RC[6], RD[6];
            load_rows(ab, j, RU, RC, RD);
            #pragma unroll
            for (int g = 0; g < G_; ++g) {
                float a0 = sA0[g], a1 = sA1[g], bc = sB[g];
                #pragma unroll
                for (int jj = 0; jj < 4; ++jj) {
                    float y = fmaf(a0, glcm_val(RU, RC, RD, jj, P0[g]),
                             fmaf(a1, glcm_val(RU, RC, RD, jj, P1[g]), bc));
                    acc[g] += fmaxf(y, 0.f);
                }
            }
        }
    }

    int lane = t & 63, wave = t >> 6;
    #pragma unroll
    for (int g = 0; g < G_; ++g) {
        float v = acc[g];
        v += __shfl_down(v, 32);
        v += __shfl_down(v, 16);
        v += __shfl_down(v, 8);
        v += __shfl_down(v, 4);
        v += __shfl_down(v, 2);
        v += __shfl_down(v, 1);
        if (lane == 0) red[wave * G_ + g] = v;
    }
    __syncthreads();
    if (t < G_) {
        partial[(size_t)(b * CHUNKS_ + chunk) * G_ + t] =
            red[t] + red[G_+t] + red[2*G_+t] + red[3*G_+t];
    }
}

// ---------------- kernel 3: attention MLP, fold to v[b,g], c[b] ----------------
__global__ void k_att(const float* __restrict__ partial,
                      const float* __restrict__ bn1_g, const float* __restrict__ bn1_b,
                      const float* __restrict__ bn1_m, const float* __restrict__ bn1_v,
                      const float* __restrict__ w1, const float* __restrict__ ca_w1,
                      const float* __restrict__ ca_w2,
                      float* __restrict__ vout, float* __restrict__ cout) {
    int b = blockIdx.x;
    int t = threadIdx.x;
    __shared__ float ss1[G_], sb1[G_];
    __shared__ float meanr[G_], pooled[G_], hid[G_/2], att[G_];
    if (t < G_) {
        float s1 = bn1_g[t] / sqrtf(bn1_v[t] + 1e-5f);
        ss1[t] = s1;
        sb1[t] = bn1_b[t] - bn1_m[t] * s1;
        float s = 0.f;
        for (int j = 0; j < CHUNKS_; ++j) s += partial[(size_t)(b * CHUNKS_ + j) * G_ + t];
        meanr[t] = s * (1.0f / (float)HW_);
    }
    __syncthreads();
    if (t < G_) {
        float s = 0.f;
        #pragma unroll
        for (int g = 0; g < G_; ++g) s += w1[t*G_ + g] * meanr[g];
        pooled[t] = fmaf(s, ss1[t], sb1[t]);
    }
    __syncthreads();
    if (t < G_/2) {
        float s = 0.f;
        #pragma unroll
        for (int o = 0; o < G_; ++o) s += pooled[o] * ca_w1[t*G_ + o];
        hid[t] = fmaxf(s, 0.f);
    }
    __syncthreads();
    if (t < G_) {
        float s = 0.f;
        #pragma unroll
        for (int k = 0; k < G_/2; ++k) s += hid[k] * ca_w2[t*(G_/2) + k];
        att[t] = 1.0f / (1.0f + expf(-s));
    }
    __syncthreads();
    if (t < G_) {
        float s = 0.f;
        #pragma unroll
        for (int o = 0; o < G_; ++o) s += att[o] * ss1[o] * w1[o*G_ + t];
        vout[b*G_ + t] = s;
    }
    if (t == 63) {
        float s = 0.f;
        #pragma unroll
        for (int o = 0; o < G_; ++o) s += att[o] * sb1[o];
        cout[b] = s;
    }
}

// ---------------- kernel 4: final output ----------------
__global__ __launch_bounds__(256) void k_out(const float* __restrict__ a,
                                             const float* __restrict__ gw,
                                             const float* __restrict__ bng_g, const float* __restrict__ bng_b,
                                             const float* __restrict__ bng_m, const float* __restrict__ bng_v,
                                             const float* __restrict__ v,
                                             const float* __restrict__ cvals,
                                             float* __restrict__ out) {
    PAIR_LISTS
    int b = blockIdx.x / CHUNKS_;
    int chunk = blockIdx.x % CHUNKS_;
    int t = threadIdx.x;
    __shared__ float sA0[G_], sA1[G_], sB[G_], sV[G_];
    __shared__ float sC;
    if (t < G_) {
        float sg = bng_g[t] / sqrtf(bng_v[t] + 1e-5f);
        sA0[t] = gw[2*t+0] * sg;
        sA1[t] = gw[2*t+1] * sg;
        sB[t]  = bng_b[t] - bng_m[t] * sg;
        sV[t]  = v[b*G_ + t];
    }
    if (t == 63) sC = cvals[b];
    __syncthreads();
    const float* ab = a + (size_t)b * HW_;
    f4v* ob4 = reinterpret_cast<f4v*>(out) + (size_t)b * HW4_;

    #pragma unroll 1
    for (int k = 0; k < 2; ++k) {
        int idx = k * 256 + t;
        if (idx < F4_PER_CHUNK_) {
            int j = chunk * F4_PER_CHUNK_ + idx;
            float RU[6], RC[6], RD[6];
            load_rows(ab, j, RU, RC, RD);
            float s0 = sC, s1 = sC, s2 = sC, s3 = sC;
            #pragma unroll
            for (int g = 0; g < G_; ++g) {
                float a0 = sA0[g], a1 = sA1[g], bc = sB[g], vg = sV[g];
                float y0 = fmaf(a0, glcm_val(RU,RC,RD,0,P0[g]), fmaf(a1, glcm_val(RU,RC,RD,0,P1[g]), bc));
                float y1 = fmaf(a0, glcm_val(RU,RC,RD,1,P0[g]), fmaf(a1, glcm_val(RU,RC,RD,1,P1[g]), bc));
                float y2 = fmaf(a0, glcm_val(RU,RC,RD,2,P0[g]), fmaf(a1, glcm_val(RU,RC,RD,2,P1[g]), bc));
                float y3 = fmaf(a0, glcm_val(RU,RC,RD,3,P0[g]), fmaf(a1, glcm_val(RU,RC,RD,3,P1[g]), bc));
                s0 = fmaf(fmaxf(y0, 0.f), vg, s0);
                s1 = fmaf(fmaxf(y1, 0.f), vg, s1);
                s2 = fmaf(fmaxf(y2, 0.f), vg, s2);
                s3 = fmaf(fmaxf(y3, 0.f), vg, s3);
            }
            f4v r;
            r.x = 1.0f / (1.0f + expf(-s0));
            r.y = 1.0f / (1.0f + expf(-s1));
            r.z = 1.0f / (1.0f + expf(-s2));
            r.w = 1.0f / (1.0f + expf(-s3));
            ob4[j] = r;
        }
    }
}

extern "C" void kernel_launch(void* const* d_in, const int* in_sizes, int n_in,
                              void* d_out, int out_size, void* d_ws, size_t ws_size,
                              hipStream_t stream) {
    const float* x     = (const float*)d_in[0];
    const float* gw    = (const float*)d_in[1];
    const float* w1    = (const float*)d_in[2];
    const float* ca_w1 = (const float*)d_in[3];
    const float* ca_w2 = (const float*)d_in[4];
    const float* bng_g = (const float*)d_in[5];
    const float* bng_b = (const float*)d_in[6];
    const float* bng_m = (const float*)d_in[7];
    const float* bng_v = (const float*)d_in[8];
    const float* bn1_g = (const float*)d_in[9];
    const float* bn1_b = (const float*)d_in[10];
    const float* bn1_m = (const float*)d_in[11];
    const float* bn1_v = (const float*)d_in[12];

    float* ws      = (float*)d_ws;
    float* a       = ws;                                   // 32*50176 floats
    float* partial = a + (size_t)B_ * HW_;                 // 32*28*36 floats
    float* v       = partial + (size_t)B_ * CHUNKS_ * G_;  // 32*36
    float* cvals   = v + B_ * G_;                          // 32

    k_mean<<<B_ * 49, 256, 0, stream>>>(x, a);
    k_sums<<<B_ * CHUNKS_, 256, 0, stream>>>(a, gw,
        bng_g, bng_b, bng_m, bng_v, partial);
    k_att<<<B_, 64, 0, stream>>>(partial,
        bn1_g, bn1_b, bn1_m, bn1_v, w1, ca_w1, ca_w2, v, cvals);
    k_out<<<B_ * CHUNKS_, 256, 0, stream>>>(a, gw,
        bng_g, bng_b, bng_m, bng_v, v, cvals, (float*)d_out);
}

// Round 3
// 127.032 us; speedup vs baseline: 2.1009x; 2.1009x over previous
//
#include <hip/hip_runtime.h>
#include <math.h>

#define B_   32
#define C_   64
#define H_   224
#define W_   224
#define HW_  (H_*W_)          // 50176
#define HW4_ (HW_/4)          // 12544
#define G_   36
#define CHUNKS_ 28
#define PIX_PER_CHUNK_ (HW_/CHUNKS_)          // 1792 = 7*256
#define PIX_PER_THREAD_ (PIX_PER_CHUNK_/256)  // 7

typedef float f4v __attribute__((ext_vector_type(4)));

// ---------------- kernel 1: channel mean ----------------
__global__ __launch_bounds__(256) void k_mean(const float* __restrict__ x,
                                              float* __restrict__ a) {
    int b = blockIdx.x / 49;                      // 49 blocks per image (49*256 = 12544 float4)
    int i = (blockIdx.x % 49) * 256 + threadIdx.x;
    const f4v* x4 = reinterpret_cast<const f4v*>(x) + (size_t)b * C_ * HW4_ + i;
    f4v s = {0.f, 0.f, 0.f, 0.f};
    #pragma unroll 8
    for (int c = 0; c < C_; ++c) {
        s += x4[(size_t)c * HW4_];
    }
    s *= (1.0f / 64.0f);
    reinterpret_cast<f4v*>(a)[(size_t)b * HW4_ + i] = s;
}

// 9 GLCM neighbor values as NAMED SCALARS (no arrays -> no scratch risk,
// no dependence on loop-unroll heuristics for static addressing).
__device__ __forceinline__ void gather9s(const float* __restrict__ ab, int p,
        float& n0, float& n1, float& n2, float& n3, float& n4,
        float& n5, float& n6, float& n7, float& n8) {
    int h = p / W_, w = p - (p / W_) * W_;
    int hm = h > 0 ? h - 1 : 0, hp = h < H_-1 ? h + 1 : H_-1;
    int wm = w > 0 ? w - 1 : 0, wp = w < W_-1 ? w + 1 : W_-1;
    n0 = ab[h*W_ + w];
    n1 = ab[h*W_ + wp];
    n2 = ab[hp*W_ + w];
    n3 = ab[hp*W_ + wp];
    n4 = ab[h*W_ + wm];
    n5 = ab[hm*W_ + w];
    n6 = n3;                        // left(up) == up(left)
    n7 = ab[hm*W_ + wp];
    n8 = ab[hm*W_ + wm];
}

// X-macro over the 36 channel pairs (g, ch0, ch1) — all compile-time literals.
#define PAIR_LIST(OP) \
  OP(0,0,1) OP(1,0,2) OP(2,0,3) OP(3,0,4) OP(4,0,5) OP(5,0,6) OP(6,0,7) OP(7,0,8) \
  OP(8,1,2) OP(9,1,3) OP(10,1,4) OP(11,1,5) OP(12,1,6) OP(13,1,7) OP(14,1,8) \
  OP(15,2,3) OP(16,2,4) OP(17,2,5) OP(18,2,6) OP(19,2,7) OP(20,2,8) \
  OP(21,3,4) OP(22,3,5) OP(23,3,6) OP(24,3,7) OP(25,3,8) \
  OP(26,4,5) OP(27,4,6) OP(28,4,7) OP(29,4,8) \
  OP(30,5,6) OP(31,5,7) OP(32,5,8) \
  OP(33,6,7) OP(34,6,8) OP(35,7,8)

// ---------------- kernel 2: per-(b,chunk) partial sums of relu(bn(grouped conv)) ----------------
__global__ __launch_bounds__(256) void k_sums(const float* __restrict__ a,
                                              const float* __restrict__ gw,
                                              const float* __restrict__ bng_g, const float* __restrict__ bng_b,
                                              const float* __restrict__ bng_m, const float* __restrict__ bng_v,
                                              float* __restrict__ partial) {
    int b = blockIdx.x / CHUNKS_;
    int chunk = blockIdx.x % CHUNKS_;
    int t = threadIdx.x;
    __shared__ float sA0[G_], sA1[G_], sB[G_];
    __shared__ float red[4 * G_];
    if (t < G_) {
        float sg = bng_g[t] / sqrtf(bng_v[t] + 1e-5f);
        sA0[t] = gw[2*t+0] * sg;
        sA1[t] = gw[2*t+1] * sg;
        sB[t]  = bng_b[t] - bng_m[t] * sg;
    }
    __syncthreads();
    const float* ab = a + (size_t)b * HW_;
    float acc[G_];
    #pragma unroll
    for (int g = 0; g < G_; ++g) acc[g] = 0.f;

    #pragma unroll 2
    for (int k = 0; k < PIX_PER_THREAD_; ++k) {
        int p = chunk * PIX_PER_CHUNK_ + k * 256 + t;
        float n0,n1,n2,n3,n4,n5,n6,n7,n8;
        gather9s(ab, p, n0,n1,n2,n3,n4,n5,n6,n7,n8);
        #define SUM_OP(g, i0, i1) { \
            float y = fmaf(sA0[g], n##i0, fmaf(sA1[g], n##i1, sB[g])); \
            acc[g] += fmaxf(y, 0.f); }
        PAIR_LIST(SUM_OP)
        #undef SUM_OP
    }

    int lane = t & 63, wave = t >> 6;
    #pragma unroll
    for (int g = 0; g < G_; ++g) {
        float v = acc[g];
        v += __shfl_down(v, 32);
        v += __shfl_down(v, 16);
        v += __shfl_down(v, 8);
        v += __shfl_down(v, 4);
        v += __shfl_down(v, 2);
        v += __shfl_down(v, 1);
        if (lane == 0) red[wave * G_ + g] = v;
    }
    __syncthreads();
    if (t < G_) {
        partial[(size_t)(b * CHUNKS_ + chunk) * G_ + t] =
            red[t] + red[G_+t] + red[2*G_+t] + red[3*G_+t];
    }
}

// ---------------- kernel 3: attention MLP, fold to v[b,g], c[b] ----------------
__global__ void k_att(const float* __restrict__ partial,
                      const float* __restrict__ bn1_g, const float* __restrict__ bn1_b,
                      const float* __restrict__ bn1_m, const float* __restrict__ bn1_v,
                      const float* __restrict__ w1, const float* __restrict__ ca_w1,
                      const float* __restrict__ ca_w2,
                      float* __restrict__ vout, float* __restrict__ cout) {
    int b = blockIdx.x;
    int t = threadIdx.x;
    __shared__ float ss1[G_], sb1[G_];
    __shared__ float meanr[G_], pooled[G_], hid[G_/2], att[G_];
    if (t < G_) {
        float s1 = bn1_g[t] / sqrtf(bn1_v[t] + 1e-5f);
        ss1[t] = s1;
        sb1[t] = bn1_b[t] - bn1_m[t] * s1;
        float s = 0.f;
        for (int j = 0; j < CHUNKS_; ++j) s += partial[(size_t)(b * CHUNKS_ + j) * G_ + t];
        meanr[t] = s * (1.0f / (float)HW_);
    }
    __syncthreads();
    if (t < G_) {
        float s = 0.f;
        #pragma unroll
        for (int g = 0; g < G_; ++g) s += w1[t*G_ + g] * meanr[g];
        pooled[t] = fmaf(s, ss1[t], sb1[t]);
    }
    __syncthreads();
    if (t < G_/2) {
        float s = 0.f;
        #pragma unroll
        for (int o = 0; o < G_; ++o) s += pooled[o] * ca_w1[t*G_ + o];
        hid[t] = fmaxf(s, 0.f);
    }
    __syncthreads();
    if (t < G_) {
        float s = 0.f;
        #pragma unroll
        for (int k = 0; k < G_/2; ++k) s += hid[k] * ca_w2[t*(G_/2) + k];
        att[t] = 1.0f / (1.0f + expf(-s));
    }
    __syncthreads();
    if (t < G_) {
        float s = 0.f;
        #pragma unroll
        for (int o = 0; o < G_; ++o) s += att[o] * ss1[o] * w1[o*G_ + t];
        vout[b*G_ + t] = s;
    }
    if (t == 63) {
        float s = 0.f;
        #pragma unroll
        for (int o = 0; o < G_; ++o) s += att[o] * sb1[o];
        cout[b] = s;
    }
}

// ---------------- kernel 4: final output ----------------
__global__ __launch_bounds__(256) void k_out(const float* __restrict__ a,
                                             const float* __restrict__ gw,
                                             const float* __restrict__ bng_g, const float* __restrict__ bng_b,
                                             const float* __restrict__ bng_m, const float* __restrict__ bng_v,
                                             const float* __restrict__ v,
                                             const float* __restrict__ cvals,
                                             float* __restrict__ out) {
    int b = blockIdx.x / CHUNKS_;
    int chunk = blockIdx.x % CHUNKS_;
    int t = threadIdx.x;
    __shared__ float sA0[G_], sA1[G_], sB[G_], sV[G_];
    __shared__ float sC;
    if (t < G_) {
        float sg = bng_g[t] / sqrtf(bng_v[t] + 1e-5f);
        sA0[t] = gw[2*t+0] * sg;
        sA1[t] = gw[2*t+1] * sg;
        sB[t]  = bng_b[t] - bng_m[t] * sg;
        sV[t]  = v[b*G_ + t];
    }
    if (t == 63) sC = cvals[b];
    __syncthreads();
    const float* ab = a + (size_t)b * HW_;
    float* ob = out + (size_t)b * HW_;
    #pragma unroll 2
    for (int k = 0; k < PIX_PER_THREAD_; ++k) {
        int p = chunk * PIX_PER_CHUNK_ + k * 256 + t;
        float n0,n1,n2,n3,n4,n5,n6,n7,n8;
        gather9s(ab, p, n0,n1,n2,n3,n4,n5,n6,n7,n8);
        float s = sC;
        #define OUT_OP(g, i0, i1) { \
            float y = fmaf(sA0[g], n##i0, fmaf(sA1[g], n##i1, sB[g])); \
            s = fmaf(fmaxf(y, 0.f), sV[g], s); }
        PAIR_LIST(OUT_OP)
        #undef OUT_OP
        ob[p] = 1.0f / (1.0f + expf(-s));
    }
}

extern "C" void kernel_launch(void* const* d_in, const int* in_sizes, int n_in,
                              void* d_out, int out_size, void* d_ws, size_t ws_size,
                              hipStream_t stream) {
    const float* x     = (const float*)d_in[0];
    const float* gw    = (const float*)d_in[1];
    const float* w1    = (const float*)d_in[2];
    const float* ca_w1 = (const float*)d_in[3];
    const float* ca_w2 = (const float*)d_in[4];
    const float* bng_g = (const float*)d_in[5];
    const float* bng_b = (const float*)d_in[6];
    const float* bng_m = (const float*)d_in[7];
    const float* bng_v = (const float*)d_in[8];
    const float* bn1_g = (const float*)d_in[9];
    const float* bn1_b = (const float*)d_in[10];
    const float* bn1_m = (const float*)d_in[11];
    const float* bn1_v = (const float*)d_in[12];

    float* ws      = (float*)d_ws;
    float* a       = ws;                                   // 32*50176 floats
    float* partial = a + (size_t)B_ * HW_;                 // 32*28*36 floats
    float* v       = partial + (size_t)B_ * CHUNKS_ * G_;  // 32*36
    float* cvals   = v + B_ * G_;                          // 32

    k_mean<<<B_ * 49, 256, 0, stream>>>(x, a);
    k_sums<<<B_ * CHUNKS_, 256, 0, stream>>>(a, gw,
        bng_g, bng_b, bng_m, bng_v, partial);
    k_att<<<B_, 64, 0, stream>>>(partial,
        bn1_g, bn1_b, bn1_m, bn1_v, w1, ca_w1, ca_w2, v, cvals);
    k_out<<<B_ * CHUNKS_, 256, 0, stream>>>(a, gw,
        bng_g, bng_b, bng_m, bng_v, v, cvals, (float*)d_out);
}